// Round 1
// baseline (2699.033 us; speedup 1.0000x reference)
//
#include <hip/hip_runtime.h>
#include <hip/hip_bf16.h>

#define NPG 26
#define EPG 52
#define HDIM 128
#define NC 7
#define NFEAT 9
#define NVOC 119
#define KCH 16

typedef unsigned int u32;
typedef unsigned short u16;

__device__ inline float bf2f(u16 u) {
    union { u32 x; float f; } c; c.x = ((u32)u) << 16; return c.f;
}

template<bool BF>
__device__ inline float ldf(const void* p, long long i) {
    if constexpr (BF) return bf2f(((const u16*)p)[i]);
    else return ((const float*)p)[i];
}

template<bool BF>
__device__ inline void stf(void* p, long long i, float v) {
    if constexpr (BF) ((__hip_bfloat16*)p)[i] = __float2bfloat16(v);
    else ((float*)p)[i] = v;
}

__device__ inline void unpack2(u32 w, float* d) {
    union { u32 x; float f; } a, b;
    a.x = (w & 0xffffu) << 16; b.x = w & 0xffff0000u;
    d[0] = a.f; d[1] = b.f;
}

// stage KCH*HDIM = 2048 elements of W (starting at element elemOff) into dst (f32)
template<bool BF>
__device__ inline void stageW(const void* W, long long elemOff, float* dst, int tid) {
    if constexpr (BF) {
        const uint4* v = (const uint4*)((const u16*)W + elemOff);  // 8 bf16 per uint4
        uint4 a = v[tid];                                          // 256*8 = 2048
        float* d = dst + tid * 8;
        unpack2(a.x, d); unpack2(a.y, d + 2); unpack2(a.z, d + 4); unpack2(a.w, d + 6);
    } else {
        const float4* v = (const float4*)((const float*)W + elemOff); // 512 float4
        ((float4*)dst)[tid]       = v[tid];
        ((float4*)dst)[tid + 256] = v[tid + 256];
    }
}

// dtype probe: low 16 bits of each u32 of a packed-bf16 weight array are a plausible
// small bf16 (|v|<1); low mantissa bits of true f32 give random exponents (~50% |v|>=1).
__global__ void probe_dtype(const void* w, int* flag) {
    if (threadIdx.x == 0 && blockIdx.x == 0) {
        const u32* p = (const u32*)w;
        int big = 0;
        for (int i = 0; i < 256; ++i) {
            union { u32 x; float f; } c; c.x = (p[i] & 0xffffu) << 16;
            float v = fabsf(c.f);
            if (!(v < 1.0f)) big++;   // counts >=1, inf, nan
        }
        *flag = (big < 16) ? 1 : 0;   // 1 = bf16, 0 = f32
    }
}

template<bool BF>
__global__ __launch_bounds__(256) void diffpool_main(
    const int* __restrict__ xfeat,
    const int* __restrict__ esrc,
    const int* __restrict__ edst,
    const void* __restrict__ emb,
    const void* __restrict__ convWl,
    const void* __restrict__ convbl,
    const void* __restrict__ convWr,
    const void* __restrict__ bng, const void* __restrict__ bnb,
    const void* __restrict__ bnrm, const void* __restrict__ bnrv,
    const void* __restrict__ aWl, const void* __restrict__ abl,
    const void* __restrict__ aWr,
    const void* __restrict__ linW, const void* __restrict__ linb,
    void* __restrict__ out, float* __restrict__ accum,
    const int* __restrict__ flag)
{
    if (*flag != (BF ? 1 : 0)) return;

    __shared__ float h_s[32][HDIM];
    __shared__ float mean_s[32][HDIM];
    __shared__ float wl_s[KCH * HDIM];
    __shared__ float wr_s[KCH * HDIM];
    __shared__ float x2e[8][HDIM];
    __shared__ float sd_s[NPG][8];
    __shared__ float adjf[NPG * NPG];
    __shared__ float red_s[256];
    __shared__ int   lsrc[EPG], ldst[EPG];
    __shared__ int   xf[NPG * NFEAT];
    __shared__ float deg_s[NPG];
    __shared__ int   cstart[NPG + 1];
    __shared__ int   ccnt[NPG];
    __shared__ int   celist[EPG];

    const int tid  = threadIdx.x;
    const int g    = blockIdx.x;
    const int j    = tid & 127;
    const int half = tid >> 7;

    // ---------------- edges, feats, CSR by dst ----------------
    if (tid < EPG) {
        lsrc[tid] = esrc[g * EPG + tid] - g * NPG;
        ldst[tid] = edst[g * EPG + tid] - g * NPG;
    }
    for (int i = tid; i < NPG * NFEAT; i += 256) xf[i] = xfeat[g * NPG * NFEAT + i];
    if (tid < NPG) ccnt[tid] = 0;
    __syncthreads();
    if (tid < EPG) atomicAdd(&ccnt[ldst[tid]], 1);
    __syncthreads();
    if (tid == 0) {
        int a = 0;
        for (int n = 0; n < NPG; ++n) { cstart[n] = a; a += ccnt[n]; }
        cstart[NPG] = a;
    }
    if (tid < NPG) deg_s[tid] = (float)ccnt[tid];
    __syncthreads();
    if (tid < NPG) ccnt[tid] = 0;
    __syncthreads();
    if (tid < EPG) {
        int d = ldst[tid];
        int pos = cstart[d] + atomicAdd(&ccnt[d], 1);
        celist[pos] = lsrc[tid];
    }

    // ---------------- atom encoder ----------------
    for (int nb = 0; nb < 13; ++nb) {
        int n = nb * 2 + half;
        float acc = 0.f;
        #pragma unroll
        for (int f = 0; f < NFEAT; ++f) {
            int v = xf[n * NFEAT + f];
            acc += ldf<BF>(emb, (long long)(f * NVOC + v) * HDIM + j);
        }
        h_s[n][j] = acc;
    }
    for (int n = NPG + half; n < 32; n += 2) { h_s[n][j] = 0.f; mean_s[n][j] = 0.f; }
    __syncthreads();

    const int jq = tid & 31, rq = tid >> 5;
    const int j0 = jq * 4, n0 = rq * 4;

    // ---------------- 2 SAGE conv layers ----------------
    for (int li = 0; li < 2; ++li) {
        // neighbor mean
        for (int nb = 0; nb < 13; ++nb) {
            int n = nb * 2 + half;
            float a = 0.f;
            int st = cstart[n], en = cstart[n + 1];
            for (int e = st; e < en; ++e) a += h_s[celist[e]][j];
            mean_s[n][j] = a / fmaxf(deg_s[n], 1.f);
        }
        __syncthreads();

        float acc[4][4];
        #pragma unroll
        for (int r = 0; r < 4; ++r)
            #pragma unroll
            for (int c = 0; c < 4; ++c) acc[r][c] = 0.f;

        long long wbase = (long long)li * HDIM * HDIM;
        for (int kc = 0; kc < HDIM; kc += KCH) {
            stageW<BF>(convWl, wbase + (long long)kc * HDIM, wl_s, tid);
            stageW<BF>(convWr, wbase + (long long)kc * HDIM, wr_s, tid);
            __syncthreads();
            #pragma unroll
            for (int k4 = 0; k4 < KCH; k4 += 4) {
                float4 mv[4], hv[4];
                #pragma unroll
                for (int r = 0; r < 4; ++r) {
                    mv[r] = *(const float4*)&mean_s[n0 + r][kc + k4];
                    hv[r] = *(const float4*)&h_s[n0 + r][kc + k4];
                }
                #pragma unroll
                for (int kk = 0; kk < 4; ++kk) {
                    const float4 wl4 = *(const float4*)&wl_s[(k4 + kk) * HDIM + j0];
                    const float4 wr4 = *(const float4*)&wr_s[(k4 + kk) * HDIM + j0];
                    #pragma unroll
                    for (int r = 0; r < 4; ++r) {
                        float m0 = (kk == 0) ? mv[r].x : (kk == 1) ? mv[r].y : (kk == 2) ? mv[r].z : mv[r].w;
                        float h0 = (kk == 0) ? hv[r].x : (kk == 1) ? hv[r].y : (kk == 2) ? hv[r].z : hv[r].w;
                        acc[r][0] += m0 * wl4.x + h0 * wr4.x;
                        acc[r][1] += m0 * wl4.y + h0 * wr4.y;
                        acc[r][2] += m0 * wl4.z + h0 * wr4.z;
                        acc[r][3] += m0 * wl4.w + h0 * wr4.w;
                    }
                }
            }
            __syncthreads();
        }

        // epilogue: bias + BN + relu + residual (writes own elements only)
        #pragma unroll
        for (int c = 0; c < 4; ++c) {
            int jj = j0 + c;
            float gma = ldf<BF>(bng,  li * HDIM + jj);
            float bta = ldf<BF>(bnb,  li * HDIM + jj);
            float rm  = ldf<BF>(bnrm, li * HDIM + jj);
            float rv  = ldf<BF>(bnrv, li * HDIM + jj);
            float bl  = ldf<BF>(convbl, li * HDIM + jj);
            float sc = gma * rsqrtf(rv + 1e-5f);
            float sh = bta - rm * sc;
            #pragma unroll
            for (int r = 0; r < 4; ++r) {
                int n = n0 + r;
                if (n < NPG) {
                    float v = (acc[r][c] + bl) * sc + sh;
                    v = fmaxf(v, 0.f);
                    h_s[n][jj] += v;
                }
            }
        }
        __syncthreads();
    }

    // ---------------- assignment conv -> s_log ----------------
    for (int nb = 0; nb < 13; ++nb) {
        int n = nb * 2 + half;
        float a = 0.f;
        int st = cstart[n], en = cstart[n + 1];
        for (int e = st; e < en; ++e) a += h_s[celist[e]][j];
        mean_s[n][j] = a / fmaxf(deg_s[n], 1.f);
    }
    for (int i = tid; i < HDIM * NC; i += 256) {
        int k = i / NC, c = i % NC;
        wl_s[k * 8 + c] = ldf<BF>(aWl, i);
        wr_s[k * 8 + c] = ldf<BF>(aWr, i);
    }
    __syncthreads();
    if (tid < NPG * NC) {
        int n = tid / NC, c = tid % NC;
        float a = ldf<BF>(abl, c);
        for (int k = 0; k < HDIM; ++k)
            a += mean_s[n][k] * wl_s[k * 8 + c] + h_s[n][k] * wr_s[k * 8 + c];
        sd_s[n][c] = a;
    }
    __syncthreads();

    // ---------------- softmax + entropy ----------------
    if (tid < NPG) {
        float mx = -1e30f;
        #pragma unroll
        for (int c = 0; c < NC; ++c) mx = fmaxf(mx, sd_s[tid][c]);
        float ex[NC]; float se = 0.f;
        #pragma unroll
        for (int c = 0; c < NC; ++c) { ex[c] = expf(sd_s[tid][c] - mx); se += ex[c]; }
        float inv = 1.f / se;
        float ent = 0.f;
        #pragma unroll
        for (int c = 0; c < NC; ++c) {
            float p = ex[c] * inv;
            sd_s[tid][c] = p;
            ent -= p * logf(p + 1e-15f);
        }
        red_s[tid] = ent;
    }
    __syncthreads();
    if (tid == 0) {
        float s = 0.f;
        for (int n = 0; n < NPG; ++n) s += red_s[n];
        atomicAdd(&accum[1], s);
    }

    // ---------------- adjacency + link loss ----------------
    for (int i = tid; i < NPG * NPG; i += 256) adjf[i] = 0.f;
    __syncthreads();
    if (tid < EPG) atomicAdd(&adjf[lsrc[tid] * NPG + ldst[tid]], 1.f);
    __syncthreads();
    float lacc = 0.f;
    for (int i = tid; i < NPG * NPG; i += 256) {
        int u = i / NPG, v = i % NPG;
        float ss = 0.f;
        #pragma unroll
        for (int c = 0; c < NC; ++c) ss += sd_s[u][c] * sd_s[v][c];
        float d = adjf[i] - ss;
        lacc += d * d;
    }
    __syncthreads();     // tid0's red_s reads (entropy) are done (it passed earlier barriers)
    red_s[tid] = lacc;
    __syncthreads();
    if (tid < 128) red_s[tid] += red_s[tid + 128];
    __syncthreads();
    if (tid < 64) red_s[tid] += red_s[tid + 64];
    __syncthreads();
    if (tid == 0) {
        float s = 0.f;
        for (int i = 0; i < 64; ++i) s += red_s[i];
        atomicAdd(&accum[0], s);
    }
    __syncthreads();

    // ---------------- x2 = s^T h  -> x2e[0..6][j] ----------------
    for (int c = half; c < NC; c += 2) {
        float a = 0.f;
        for (int n = 0; n < NPG; ++n) a += sd_s[n][c] * h_s[n][j];
        x2e[c][j] = a;
    }
    __syncthreads();

    // ---------------- pooled dense layers li = 2,3 ----------------
    for (int li = 2; li < 4; ++li) {
        if (half == 0) {
            float s = 0.f;
            #pragma unroll
            for (int c = 0; c < NC; ++c) s += x2e[c][j];
            x2e[7][j] = s * (1.f / 7.f);
        }
        __syncthreads();
        long long wbase = (long long)li * HDIM * HDIM;
        if (half == 0) {
            float a = ldf<BF>(convbl, li * HDIM + j);
            for (int k = 0; k < HDIM; ++k)
                a += x2e[7][k] * ldf<BF>(convWl, wbase + (long long)k * HDIM + j);
            red_s[j] = a;
        }
        __syncthreads();
        float gma = ldf<BF>(bng,  li * HDIM + j);
        float bta = ldf<BF>(bnb,  li * HDIM + j);
        float rm  = ldf<BF>(bnrm, li * HDIM + j);
        float rv  = ldf<BF>(bnrv, li * HDIM + j);
        float sc = gma * rsqrtf(rv + 1e-5f);
        float sh = bta - rm * sc;
        float hnew[4]; int nr = 0;
        for (int c = half; c < NC; c += 2) {
            float a = 0.f;
            for (int k = 0; k < HDIM; ++k)
                a += x2e[c][k] * ldf<BF>(convWr, wbase + (long long)k * HDIM + j);
            a += red_s[j];
            a = a * sc + sh;     // BN, no relu
            a += x2e[c][j];      // residual
            hnew[nr++] = a;
        }
        __syncthreads();
        nr = 0;
        for (int c = half; c < NC; c += 2) x2e[c][j] = hnew[nr++];
        __syncthreads();
    }

    // ---------------- readout ----------------
    if (half == 0) {
        float s = 0.f;
        #pragma unroll
        for (int c = 0; c < NC; ++c) s += x2e[c][j];
        s *= (1.f / 7.f);
        red_s[j] = s * ldf<BF>(linW, j);
    }
    __syncthreads();
    if (tid == 0) {
        float z = ldf<BF>(linb, 0);
        for (int i = 0; i < HDIM; ++i) z += red_s[i];
        float o = 1.f / (1.f + expf(-z));
        stf<BF>(out, g, o);
    }
}

template<bool BF>
__global__ void diffpool_finalize(const float* __restrict__ accum,
                                  const int* __restrict__ flag,
                                  void* __restrict__ out, int nb) {
    if (*flag != (BF ? 1 : 0)) return;
    if (threadIdx.x == 0 && blockIdx.x == 0) {
        float link = sqrtf(accum[0]) / ((float)nb * (float)(NPG * NPG));
        float ent  = accum[1] / ((float)nb * (float)NPG);
        stf<BF>(out, nb, link);
        stf<BF>(out, nb + 1, ent);
    }
}

extern "C" void kernel_launch(void* const* d_in, const int* in_sizes, int n_in,
                              void* d_out, int out_size, void* d_ws, size_t ws_size,
                              hipStream_t stream) {
    const int* x  = (const int*)d_in[0];
    const int* ei = (const int*)d_in[1];
    const int ntot = in_sizes[0] / NFEAT;
    const int nb   = ntot / NPG;            // number of graphs
    const int* esrc = ei;
    const int* edst = ei + (long long)nb * EPG;

    float* accum = (float*)d_ws;            // [0]=link sum, [1]=ent sum
    int*   flag  = (int*)d_ws + 2;
    hipMemsetAsync(d_ws, 0, 16, stream);
    probe_dtype<<<1, 64, 0, stream>>>(d_in[4], flag);

    diffpool_main<true><<<nb, 256, 0, stream>>>(
        x, esrc, edst, d_in[3], d_in[4], d_in[5], d_in[6],
        d_in[7], d_in[8], d_in[9], d_in[10],
        d_in[11], d_in[12], d_in[13], d_in[14], d_in[15],
        d_out, accum, flag);
    diffpool_main<false><<<nb, 256, 0, stream>>>(
        x, esrc, edst, d_in[3], d_in[4], d_in[5], d_in[6],
        d_in[7], d_in[8], d_in[9], d_in[10],
        d_in[11], d_in[12], d_in[13], d_in[14], d_in[15],
        d_out, accum, flag);

    diffpool_finalize<true><<<1, 64, 0, stream>>>(accum, flag, d_out, nb);
    diffpool_finalize<false><<<1, 64, 0, stream>>>(accum, flag, d_out, nb);
}

// Round 2
// 953.333 us; speedup vs baseline: 2.8312x; 2.8312x over previous
//
#include <hip/hip_runtime.h>
#include <hip/hip_bf16.h>

#define NPG 26
#define EPG 52
#define HDIM 128
#define NC 7
#define NFEAT 9
#define NVOC 119

typedef unsigned int u32;
typedef unsigned short u16;
typedef float f32x4 __attribute__((ext_vector_type(4)));
typedef short short8 __attribute__((ext_vector_type(8)));

__device__ inline float b2f(u16 u){ union{u32 x; float f;} c; c.x = ((u32)u)<<16; return c.f; }
__device__ inline u16 f2b(float v){ union{ __hip_bfloat16 h; u16 u;} c; c.h = __float2bfloat16(v); return c.u; }

template<bool BF>
__device__ inline float ldf(const void* p, long long i){ if constexpr (BF) return b2f(((const u16*)p)[i]); else return ((const float*)p)[i]; }
template<bool BF>
__device__ inline void stf(void* p, long long i, float v){ if constexpr (BF) ((u16*)p)[i] = f2b(v); else ((float*)p)[i] = v; }

__device__ inline f32x4 mfma16(short8 a, short8 b, f32x4 c){
  return __builtin_amdgcn_mfma_f32_16x16x32_bf16(a, b, c, 0, 0, 0);
}

struct StReg { uint4 a, b; };

// load one 32x128 chunk (chunk c of stacked [Wl;Wr], K=256) into regs; thread t covers
// row kr=t>>3, cols j0..j0+15
template<bool BF>
__device__ inline StReg stage_load(const void* Wl, const void* Wr, int li, int c, int tid){
  const int kr = tid>>3, j0 = (tid&7)*16;
  const void* W = (c<4) ? Wl : Wr;
  long long base = (long long)li*HDIM*HDIM + (long long)(c&3)*32*HDIM + (long long)kr*HDIM + j0;
  StReg r;
  if constexpr (BF) {
    const uint4* p = (const uint4*)((const u16*)W + base);
    r.a = p[0]; r.b = p[1];
  } else {
    const float* p = (const float*)W + base;
    alignas(16) u16 t[16];
    #pragma unroll
    for (int i=0;i<16;++i) t[i] = f2b(p[i]);
    r.a = *(const uint4*)&t[0]; r.b = *(const uint4*)&t[8];
  }
  return r;
}

// dtype probe (bf16 vs f32) as in R1
__global__ void probe_dtype(const void* w, int* flag) {
  if (threadIdx.x == 0 && blockIdx.x == 0) {
    const u32* p = (const u32*)w;
    int big = 0;
    for (int i = 0; i < 256; ++i) {
      union { u32 x; float f; } c; c.x = (p[i] & 0xffffu) << 16;
      float v = fabsf(c.f);
      if (!(v < 1.0f)) big++;
    }
    *flag = (big < 16) ? 1 : 0;
  }
}

template<bool BF>
__global__ __launch_bounds__(256, 4) void diffpool_main(
    const int* __restrict__ xfeat,
    const int* __restrict__ esrc,
    const int* __restrict__ edst,
    const void* __restrict__ emb,
    const void* __restrict__ convWl,
    const void* __restrict__ convbl,
    const void* __restrict__ convWr,
    const void* __restrict__ bng, const void* __restrict__ bnb,
    const void* __restrict__ bnrm, const void* __restrict__ bnrv,
    const void* __restrict__ aWl, const void* __restrict__ abl,
    const void* __restrict__ aWr,
    const void* __restrict__ linW, const void* __restrict__ linb,
    void* __restrict__ out, float* __restrict__ accum,
    const int* __restrict__ flag)
{
  if (*flag != (BF ? 1 : 0)) return;

  // A-matrix: rows = nodes (26 + 6 zero pad), k = [mean(0..127) | h(128..255)] + pad
  __shared__ alignas(16) u16 ab[32][264];
  __shared__ alignas(16) u16 wbuf[32][136];     // staged 32x128 weight chunk (row-major [k][j])
  __shared__ alignas(16) u16 x2ab[16][264];     // pooled A: [m | x2_c]; also overlaid as abuf
  __shared__ alignas(16) u16 sdT[16][40];       // s^T: [c][n] bf16, zero padded
  __shared__ float sd_s[NPG][8];                // logits then probs (f32)
  __shared__ float red_s[256];
  __shared__ int lsrc[EPG], ldst[EPG], celist[EPG];
  __shared__ int cstart[NPG+1], ccnt[NPG];
  __shared__ float rdeg[NPG];
  __shared__ int xf[NPG*NFEAT];

  const int tid  = threadIdx.x;
  const int g    = blockIdx.x;
  const int j    = tid & 127;
  const int half = tid >> 7;
  const int w    = tid >> 6;        // wave id 0..3
  const int lane = tid & 63;
  const int l4   = lane >> 4;       // 0..3
  const int lm   = lane & 15;       // 0..15
  const int jc0  = w*32 + lm, jc1 = jc0 + 16;   // output cols owned by this lane

  // ---------------- load edges/features, CSR by dst ----------------
  if (tid < EPG) {
    lsrc[tid] = esrc[(long long)g*EPG + tid] - g*NPG;
    ldst[tid] = edst[(long long)g*EPG + tid] - g*NPG;
  }
  for (int i = tid; i < NPG*NFEAT; i += 256) xf[i] = xfeat[(long long)g*NPG*NFEAT + i];
  if (tid < NPG) ccnt[tid] = 0;
  for (int i = tid; i < 16*40; i += 256) ((u16*)sdT)[i] = 0;
  for (int i = tid; i < 6*264; i += 256) ab[26 + i/264][i%264] = 0;  // zero pad rows
  __syncthreads();
  if (tid < EPG) atomicAdd(&ccnt[ldst[tid]], 1);
  __syncthreads();
  if (tid == 0) { int a = 0; for (int n = 0; n < NPG; ++n){ cstart[n] = a; a += ccnt[n]; } cstart[NPG] = a; }
  if (tid < NPG) rdeg[tid] = 1.f / fmaxf((float)ccnt[tid], 1.f);
  __syncthreads();
  if (tid < NPG) ccnt[tid] = 0;
  __syncthreads();
  if (tid < EPG) { int d = ldst[tid]; int pos = cstart[d] + atomicAdd(&ccnt[d], 1); celist[pos] = lsrc[tid]; }

  // ---------------- atom encoder -> h region of ab ----------------
  for (int nb2 = 0; nb2 < 13; ++nb2) {
    int n = nb2*2 + half;
    float acc = 0.f;
    #pragma unroll
    for (int f = 0; f < NFEAT; ++f)
      acc += ldf<BF>(emb, (long long)(f*NVOC + xf[n*NFEAT + f])*HDIM + j);
    ab[n][128 + j] = f2b(acc);
  }
  __syncthreads();

  // ---------------- 2 SAGE conv layers (MFMA) ----------------
  for (int li = 0; li < 2; ++li) {
    // neighbor mean -> ab[:,0:128]
    for (int nb2 = 0; nb2 < 13; ++nb2) {
      int n = nb2*2 + half;
      float a = 0.f;
      for (int e = cstart[n]; e < cstart[n+1]; ++e) a += b2f(ab[celist[e]][128 + j]);
      ab[n][j] = f2b(a * rdeg[n]);
    }
    __syncthreads();

    f32x4 a00 = {0,0,0,0}, a01 = {0,0,0,0}, a10 = {0,0,0,0}, a11 = {0,0,0,0};
    StReg r = stage_load<BF>(convWl, convWr, li, 0, tid);
    for (int c = 0; c < 8; ++c) {
      __syncthreads();      // prev chunk's B reads done
      { int kr = tid>>3, j0 = (tid&7)*16;
        *(uint4*)&wbuf[kr][j0] = r.a; *(uint4*)&wbuf[kr][j0+8] = r.b; }
      if (c < 7) r = stage_load<BF>(convWl, convWr, li, c+1, tid);  // prefetch next
      __syncthreads();      // wbuf ready
      const int kb = c*32 + 8*l4;
      short8 af0 = *(const short8*)&ab[lm][kb];
      short8 af1 = *(const short8*)&ab[16 + lm][kb];
      short8 b0, b1;
      #pragma unroll
      for (int i = 0; i < 8; ++i) { b0[i] = (short)wbuf[8*l4 + i][jc0]; b1[i] = (short)wbuf[8*l4 + i][jc1]; }
      a00 = mfma16(af0, b0, a00); a01 = mfma16(af0, b1, a01);
      a10 = mfma16(af1, b0, a10); a11 = mfma16(af1, b1, a11);
    }
    __syncthreads();        // all A/B reads done before h writes

    const long long pb = (long long)li*HDIM;
    float sc0 = ldf<BF>(bng, pb+jc0) * rsqrtf(ldf<BF>(bnrv, pb+jc0) + 1e-5f);
    float sh0 = ldf<BF>(bnb, pb+jc0) - ldf<BF>(bnrm, pb+jc0)*sc0;
    float bl0 = ldf<BF>(convbl, pb+jc0);
    float sc1 = ldf<BF>(bng, pb+jc1) * rsqrtf(ldf<BF>(bnrv, pb+jc1) + 1e-5f);
    float sh1 = ldf<BF>(bnb, pb+jc1) - ldf<BF>(bnrm, pb+jc1)*sc1;
    float bl1 = ldf<BF>(convbl, pb+jc1);
    #pragma unroll
    for (int rr = 0; rr < 4; ++rr) {
      int n = 4*l4 + rr;
      if (n < NPG) {
        float v0 = fmaxf((a00[rr] + bl0)*sc0 + sh0, 0.f);
        float v1 = fmaxf((a01[rr] + bl1)*sc1 + sh1, 0.f);
        ab[n][128+jc0] = f2b(v0 + b2f(ab[n][128+jc0]));
        ab[n][128+jc1] = f2b(v1 + b2f(ab[n][128+jc1]));
      }
      int n1 = 16 + 4*l4 + rr;
      if (n1 < NPG) {
        float v0 = fmaxf((a10[rr] + bl0)*sc0 + sh0, 0.f);
        float v1 = fmaxf((a11[rr] + bl1)*sc1 + sh1, 0.f);
        ab[n1][128+jc0] = f2b(v0 + b2f(ab[n1][128+jc0]));
        ab[n1][128+jc1] = f2b(v1 + b2f(ab[n1][128+jc1]));
      }
    }
    __syncthreads();
  }

  // ---------------- assignment conv (MFMA, waves 0-1) ----------------
  for (int nb2 = 0; nb2 < 13; ++nb2) {
    int n = nb2*2 + half;
    float a = 0.f;
    for (int e = cstart[n]; e < cstart[n+1]; ++e) a += b2f(ab[celist[e]][128 + j]);
    ab[n][j] = f2b(a * rdeg[n]);
  }
  u16 (*abuf)[16] = reinterpret_cast<u16(*)[16]>(&x2ab[0][0]);  // [aWl;aWr] staged [k][c]
  {
    int k = tid;  // 256 rows
    #pragma unroll
    for (int c = 0; c < NC; ++c) {
      long long idx = (long long)(k & 127)*NC + c;
      abuf[k][c] = BF ? ((const u16*)(k < 128 ? aWl : aWr))[idx]
                      : f2b(((const float*)(k < 128 ? aWl : aWr))[idx]);
    }
    #pragma unroll
    for (int c = NC; c < 16; ++c) abuf[k][c] = 0;
  }
  __syncthreads();
  if (w < 2) {
    f32x4 acc = {0,0,0,0};
    #pragma unroll
    for (int c = 0; c < 8; ++c) {
      const int kb = c*32 + 8*l4;
      short8 af = *(const short8*)&ab[w*16 + lm][kb];
      short8 bfv;
      #pragma unroll
      for (int i = 0; i < 8; ++i) bfv[i] = (short)abuf[kb + i][lm];
      acc = mfma16(af, bfv, acc);
    }
    float bl = (lm < NC) ? ldf<BF>(abl, lm) : 0.f;
    #pragma unroll
    for (int rr = 0; rr < 4; ++rr) {
      int n = w*16 + 4*l4 + rr;
      if (n < NPG && lm < NC) sd_s[n][lm] = acc[rr] + bl;
    }
  }
  __syncthreads();

  // ---------------- softmax (probs stay f32) ----------------
  if (tid < NPG) {
    float mx = -1e30f;
    #pragma unroll
    for (int c = 0; c < NC; ++c) mx = fmaxf(mx, sd_s[tid][c]);
    float se = 0.f, ex[NC];
    #pragma unroll
    for (int c = 0; c < NC; ++c) { ex[c] = expf(sd_s[tid][c] - mx); se += ex[c]; }
    float inv = 1.f/se;
    #pragma unroll
    for (int c = 0; c < NC; ++c) sd_s[tid][c] = ex[c]*inv;
  }
  __syncthreads();
  if (tid < NPG*NC) { int n = tid/7, c = tid%7; sdT[c][n] = f2b(sd_s[n][c]); }

  // ---------------- link loss: sum c^2 - 2*sum_e ss_e + ||S^T S||_F^2 ----------------
  float lv = 0.f;
  if (tid < EPG) {
    int key = lsrc[tid]*32 + ldst[tid];
    int cnt = 0;
    for (int e = 0; e < EPG; ++e) cnt += ((lsrc[e]*32 + ldst[e]) == key) ? 1 : 0;
    float ss = 0.f;
    #pragma unroll
    for (int c = 0; c < NC; ++c) ss += sd_s[lsrc[tid]][c]*sd_s[ldst[tid]][c];
    lv = (float)cnt - 2.f*ss;
  } else if (tid >= 64 && tid < 64 + NC*NC) {
    int idx = tid - 64, c1 = idx/7, c2 = idx%7;
    float m = 0.f;
    for (int n = 0; n < NPG; ++n) m += sd_s[n][c1]*sd_s[n][c2];
    lv = m*m;
  }
  red_s[tid] = lv;
  __syncthreads();
  if (tid < 128) red_s[tid] += red_s[tid+128];
  __syncthreads();
  if (tid < 64) {
    float v = red_s[tid] + red_s[tid+64];
    #pragma unroll
    for (int off = 32; off >= 1; off >>= 1) v += __shfl_down(v, off);
    if (tid == 0) atomicAdd(&accum[0], v);
  }
  __syncthreads();

  // ---------------- entropy ----------------
  float ev = 0.f;
  if (tid < NPG*NC) { float p = sd_s[tid/7][tid%7]; ev = -p*logf(p + 1e-15f); }
  red_s[tid] = ev;
  __syncthreads();
  if (tid < 128) red_s[tid] += red_s[tid+128];
  __syncthreads();
  if (tid < 64) {
    float v = red_s[tid] + red_s[tid+64];
    #pragma unroll
    for (int off = 32; off >= 1; off >>= 1) v += __shfl_down(v, off);
    if (tid == 0) atomicAdd(&accum[1], v);
  }
  __syncthreads();

  // ---------------- x2 = s^T h  (MFMA, K=32 covers all nodes) ----------------
  {
    f32x4 e0 = {0,0,0,0}, e1 = {0,0,0,0};
    short8 af = *(const short8*)&sdT[lm][8*l4];
    short8 b0, b1;
    #pragma unroll
    for (int i = 0; i < 8; ++i) { int n = 8*l4 + i; b0[i] = (short)ab[n][128+jc0]; b1[i] = (short)ab[n][128+jc1]; }
    e0 = mfma16(af, b0, e0); e1 = mfma16(af, b1, e1);
    #pragma unroll
    for (int rr = 0; rr < 4; ++rr) {
      int cc = 4*l4 + rr;
      if (cc < NC) { x2ab[cc][128+jc0] = f2b(e0[rr]); x2ab[cc][128+jc1] = f2b(e1[rr]); }
    }
  }
  __syncthreads();

  // ---------------- pooled dense layers li=2,3 (MFMA, M-tile=16) ----------------
  for (int li = 2; li < 4; ++li) {
    if (tid < 128) {
      float s = 0.f;
      #pragma unroll
      for (int c = 0; c < NC; ++c) s += b2f(x2ab[c][128 + tid]);
      u16 mb = f2b(s * (1.f/7.f));
      #pragma unroll
      for (int c = 0; c < NC; ++c) x2ab[c][tid] = mb;
    }
    __syncthreads();
    f32x4 a0 = {0,0,0,0}, a1 = {0,0,0,0};
    StReg r = stage_load<BF>(convWl, convWr, li, 0, tid);
    for (int c = 0; c < 8; ++c) {
      __syncthreads();
      { int kr = tid>>3, j0 = (tid&7)*16;
        *(uint4*)&wbuf[kr][j0] = r.a; *(uint4*)&wbuf[kr][j0+8] = r.b; }
      if (c < 7) r = stage_load<BF>(convWl, convWr, li, c+1, tid);
      __syncthreads();
      const int kb = c*32 + 8*l4;
      short8 af = *(const short8*)&x2ab[lm][kb];
      short8 b0, b1;
      #pragma unroll
      for (int i = 0; i < 8; ++i) { b0[i] = (short)wbuf[8*l4 + i][jc0]; b1[i] = (short)wbuf[8*l4 + i][jc1]; }
      a0 = mfma16(af, b0, a0); a1 = mfma16(af, b1, a1);
    }
    __syncthreads();
    const long long pb = (long long)li*HDIM;
    float sc0 = ldf<BF>(bng, pb+jc0) * rsqrtf(ldf<BF>(bnrv, pb+jc0) + 1e-5f);
    float sh0 = ldf<BF>(bnb, pb+jc0) - ldf<BF>(bnrm, pb+jc0)*sc0;
    float bl0 = ldf<BF>(convbl, pb+jc0);
    float sc1 = ldf<BF>(bng, pb+jc1) * rsqrtf(ldf<BF>(bnrv, pb+jc1) + 1e-5f);
    float sh1 = ldf<BF>(bnb, pb+jc1) - ldf<BF>(bnrm, pb+jc1)*sc1;
    float bl1 = ldf<BF>(convbl, pb+jc1);
    #pragma unroll
    for (int rr = 0; rr < 4; ++rr) {
      int cc = 4*l4 + rr;
      if (cc < NC) {
        float v0 = (a0[rr] + bl0)*sc0 + sh0 + b2f(x2ab[cc][128+jc0]);
        float v1 = (a1[rr] + bl1)*sc1 + sh1 + b2f(x2ab[cc][128+jc1]);
        x2ab[cc][128+jc0] = f2b(v0);
        x2ab[cc][128+jc1] = f2b(v1);
      }
    }
    __syncthreads();
  }

  // ---------------- readout ----------------
  if (tid < 128) {
    float s = 0.f;
    #pragma unroll
    for (int c = 0; c < NC; ++c) s += b2f(x2ab[c][128 + tid]);
    red_s[tid] = (s * (1.f/7.f)) * ldf<BF>(linW, tid);
  }
  __syncthreads();
  if (tid < 64) {
    float v = red_s[tid] + red_s[tid+64];
    #pragma unroll
    for (int off = 32; off >= 1; off >>= 1) v += __shfl_down(v, off);
    if (tid == 0) {
      float z = v + ldf<BF>(linb, 0);
      stf<BF>(out, g, 1.f/(1.f + expf(-z)));
    }
  }
}

template<bool BF>
__global__ void diffpool_finalize(const float* __restrict__ accum,
                                  const int* __restrict__ flag,
                                  void* __restrict__ out, int nb) {
  if (*flag != (BF ? 1 : 0)) return;
  if (threadIdx.x == 0 && blockIdx.x == 0) {
    float link = sqrtf(fmaxf(accum[0], 0.f)) / ((float)nb * (float)(NPG*NPG));
    float ent  = accum[1] / ((float)nb * (float)NPG);
    stf<BF>(out, nb, link);
    stf<BF>(out, nb + 1, ent);
  }
}

extern "C" void kernel_launch(void* const* d_in, const int* in_sizes, int n_in,
                              void* d_out, int out_size, void* d_ws, size_t ws_size,
                              hipStream_t stream) {
  const int* x  = (const int*)d_in[0];
  const int* ei = (const int*)d_in[1];
  const int ntot = in_sizes[0] / NFEAT;
  const int nb   = ntot / NPG;
  const int* esrc = ei;
  const int* edst = ei + (long long)nb * EPG;

  float* accum = (float*)d_ws;   // [0]=link sum of squares, [1]=ent sum
  int*   flag  = (int*)d_ws + 2;
  hipMemsetAsync(d_ws, 0, 16, stream);
  probe_dtype<<<1, 64, 0, stream>>>(d_in[4], flag);

  diffpool_main<true><<<nb, 256, 0, stream>>>(
      x, esrc, edst, d_in[3], d_in[4], d_in[5], d_in[6],
      d_in[7], d_in[8], d_in[9], d_in[10],
      d_in[11], d_in[12], d_in[13], d_in[14], d_in[15],
      d_out, accum, flag);
  diffpool_main<false><<<nb, 256, 0, stream>>>(
      x, esrc, edst, d_in[3], d_in[4], d_in[5], d_in[6],
      d_in[7], d_in[8], d_in[9], d_in[10],
      d_in[11], d_in[12], d_in[13], d_in[14], d_in[15],
      d_out, accum, flag);

  diffpool_finalize<true><<<1, 64, 0, stream>>>(accum, flag, d_out, nb);
  diffpool_finalize<false><<<1, 64, 0, stream>>>(accum, flag, d_out, nb);
}